// Round 1
// baseline (132.353 us; speedup 1.0000x reference)
//
#include <hip/hip_runtime.h>
#include <hip/hip_bf16.h>

// Segment-mean gather (AGGR_MEAN graph pooling).
//   input  [N_NODES=100000, C=128] f32
//   idxn   [E] int   (fine-node index per edge)
//   seg_ids[E] int   (sorted coarse-segment id per edge)
//   degs   [N_OUT=50000] int
//   out    [N_OUT, C] f32 = mean over edges of input[idxn[e]], 0 if deg==0
//
// One wave (64 lanes) per segment; each lane owns 2 channels (float2 -> the
// wave reads exactly one 512B row per edge, fully coalesced). Segment start
// found via wave-uniform binary search in sorted seg_ids (avoids a prefix-scan
// kernel + workspace).

__global__ __launch_bounds__(64) void seg_mean_kernel(
    const float* __restrict__ input,
    const int* __restrict__ idxn,
    const int* __restrict__ seg_ids,
    const int* __restrict__ degs,
    float* __restrict__ out,
    int n_out, int E) {
  const int s = blockIdx.x;
  if (s >= n_out) return;

  const int deg = degs[s];
  const int t = threadIdx.x;  // 0..63, lane == thread (1 wave per block)

  // lower_bound(seg_ids, s): first edge belonging to segment s.
  // Wave-uniform (every lane loads the same address -> broadcast).
  int lo = 0, hi = E;
  while (lo < hi) {
    int mid = (lo + hi) >> 1;
    if (seg_ids[mid] < s) lo = mid + 1; else hi = mid;
  }
  const int start = lo;

  const float2* __restrict__ in2 = (const float2*)input;
  float accx = 0.f, accy = 0.f;

  for (int e = 0; e < deg; ++e) {
    const int node = idxn[start + e];
    const float2 v = in2[(size_t)node * 64 + t];
    accx += v.x;
    accy += v.y;
  }

  const float inv = (deg > 0) ? (1.0f / (float)deg) : 0.0f;
  float2* out2 = (float2*)out;
  float2 r;
  r.x = accx * inv;
  r.y = accy * inv;
  out2[(size_t)s * 64 + t] = r;
}

extern "C" void kernel_launch(void* const* d_in, const int* in_sizes, int n_in,
                              void* d_out, int out_size, void* d_ws, size_t ws_size,
                              hipStream_t stream) {
  const float* input  = (const float*)d_in[0];
  const int* idxn     = (const int*)d_in[1];
  const int* seg_ids  = (const int*)d_in[2];
  const int* degs     = (const int*)d_in[3];
  float* out          = (float*)d_out;

  const int E     = in_sizes[1];
  const int n_out = in_sizes[3];

  seg_mean_kernel<<<n_out, 64, 0, stream>>>(input, idxn, seg_ids, degs, out,
                                            n_out, E);
}

// Round 2
// 120.335 us; speedup vs baseline: 1.0999x; 1.0999x over previous
//
#include <hip/hip_runtime.h>
#include <hip/hip_bf16.h>

// Segment-mean gather (AGGR_MEAN graph pooling).
//   input  [N_NODES=100000, C=128] f32
//   idxn   [E] int   (fine-node index per edge)
//   seg_ids[E] int   (sorted coarse-segment id per edge)
//   degs   [N_OUT=50000] int
//   out    [N_OUT, C] f32 = mean over edges of input[idxn[e]], 0 if deg==0
//
// One wave (64 lanes) per segment; lane owns 2 channels (float2 -> one 512B
// row per load, fully coalesced). R1: 8-way edge unroll — 8 independent row
// gathers in flight per wave (latency-bound fix: VGPR was 8, 1 load in
// flight; now ~26 MB in flight chip-wide).

__global__ __launch_bounds__(64) void seg_mean_kernel(
    const float* __restrict__ input,
    const int* __restrict__ idxn,
    const int* __restrict__ seg_ids,
    const int* __restrict__ degs,
    float* __restrict__ out,
    int n_out, int E) {
  const int s = blockIdx.x;
  if (s >= n_out) return;

  const int deg = degs[s];
  const int t = threadIdx.x;  // 0..63, 1 wave per block

  // lower_bound(seg_ids, s): first edge of segment s (wave-uniform).
  int lo = 0, hi = E;
  while (lo < hi) {
    int mid = (lo + hi) >> 1;
    if (seg_ids[mid] < s) lo = mid + 1; else hi = mid;
  }
  const int start = lo;

  const float2* __restrict__ in2 = (const float2*)input;
  float accx = 0.f, accy = 0.f;

  int e = 0;
  for (; e + 8 <= deg; e += 8) {
    int n[8];
#pragma unroll
    for (int k = 0; k < 8; ++k) n[k] = idxn[start + e + k];
    float2 v[8];
#pragma unroll
    for (int k = 0; k < 8; ++k) v[k] = in2[(size_t)n[k] * 64 + t];
#pragma unroll
    for (int k = 0; k < 8; ++k) { accx += v[k].x; accy += v[k].y; }
  }
  // tail
  for (; e < deg; ++e) {
    const int node = idxn[start + e];
    const float2 v = in2[(size_t)node * 64 + t];
    accx += v.x;
    accy += v.y;
  }

  const float inv = (deg > 0) ? (1.0f / (float)deg) : 0.0f;
  float2* out2 = (float2*)out;
  float2 r;
  r.x = accx * inv;
  r.y = accy * inv;
  out2[(size_t)s * 64 + t] = r;
}

extern "C" void kernel_launch(void* const* d_in, const int* in_sizes, int n_in,
                              void* d_out, int out_size, void* d_ws, size_t ws_size,
                              hipStream_t stream) {
  const float* input  = (const float*)d_in[0];
  const int* idxn     = (const int*)d_in[1];
  const int* seg_ids  = (const int*)d_in[2];
  const int* degs     = (const int*)d_in[3];
  float* out          = (float*)d_out;

  const int E     = in_sizes[1];
  const int n_out = in_sizes[3];

  seg_mean_kernel<<<n_out, 64, 0, stream>>>(input, idxn, seg_ids, degs, out,
                                            n_out, E);
}